// Round 2
// baseline (364.009 us; speedup 1.0000x reference)
//
#include <hip/hip_runtime.h>
#include <hip/hip_bf16.h>
#include <stdint.h>

// Shapes (fixed for this problem)
#define TOKENS 8192   // b*s = 4*2048
#define H 2048
#define JDIM 2048
#define NADAPT 64
#define RANK 16
#define KG 1024       // NADAPT*RANK
#define KTOT 3072     // H + KG

typedef __bf16 v8bf __attribute__((ext_vector_type(8)));
typedef float v4f __attribute__((ext_vector_type(4)));
typedef unsigned short us8 __attribute__((ext_vector_type(8)));
typedef unsigned short us4 __attribute__((ext_vector_type(4)));

__device__ __forceinline__ unsigned short f2bf(float f) {
  union { __bf16 b; unsigned short u; } c; c.b = (__bf16)f; return c.u;
}
__device__ __forceinline__ float bf2f(unsigned short u) {
  union { unsigned int u; float f; } c; c.u = ((unsigned int)u) << 16; return c.f;
}

__device__ __forceinline__ us8 pack8(float4 a, float4 b) {
  us8 r;
  r[0]=f2bf(a.x); r[1]=f2bf(a.y); r[2]=f2bf(a.z); r[3]=f2bf(a.w);
  r[4]=f2bf(b.x); r[5]=f2bf(b.y); r[6]=f2bf(b.z); r[7]=f2bf(b.w);
  return r;
}

__device__ __forceinline__ void split4(float4 v, us4& h, us4& l) {
  h[0]=f2bf(v.x); l[0]=f2bf(v.x - bf2f(h[0]));
  h[1]=f2bf(v.y); l[1]=f2bf(v.y - bf2f(h[1]));
  h[2]=f2bf(v.z); l[2]=f2bf(v.z - bf2f(h[2]));
  h[3]=f2bf(v.w); l[3]=f2bf(v.w - bf2f(h[3]));
}

// fp32 [rows][2048] -> bf16 [rows][dstld] (fills cols 0..2047). grid = rows blocks x 256.
__global__ void cast2048_kernel(const float* __restrict__ src,
                                unsigned short* __restrict__ dst, int dstld) {
  int idx = blockIdx.x * 256 + threadIdx.x;
  int row = idx >> 8;
  int cg  = idx & 255;
  const float4* s = (const float4*)(src + ((size_t)row << 11) + ((size_t)cg << 3));
  float4 a = s[0], b = s[1];
  *(us8*)(dst + (size_t)row * dstld + ((size_t)cg << 3)) = pack8(a, b);
}

// B [64][2048][16] fp32 -> WB[j][2048 + a*16 + r] bf16. One thread per (a,j).
__global__ void cast_b_kernel(const float* __restrict__ Bsrc,
                              unsigned short* __restrict__ WB) {
  int idx = blockIdx.x * 256 + threadIdx.x;   // 131072 total
  int a = idx >> 11, j = idx & 2047;
  const float4* s = (const float4*)(Bsrc + (((size_t)a << 11) + j) * RANK);
  float4 f0 = s[0], f1 = s[1], f2 = s[2], f3 = s[3];
  us8* d = (us8*)(WB + (size_t)j * KTOT + H + a * RANK);
  d[0] = pack8(f0, f1);
  d[1] = pack8(f2, f3);
}

// Per token: arrows = sumsq over r, top-4 adapters, G row = routes*v.
// One wave per token, 4 tokens/block.
__global__ void route_kernel(const float* __restrict__ vecs,
                             unsigned short* __restrict__ XG) {
  __shared__ float vsh[4][16];
  int wave = threadIdx.x >> 6, lane = threadIdx.x & 63;
  int t = blockIdx.x * 4 + wave;
  const float* vrow = vecs + (size_t)t * KG;
  const float4* vp = (const float4*)(vrow + lane * RANK);
  float4 q0 = vp[0], q1 = vp[1], q2 = vp[2], q3 = vp[3];
  float ss = q0.x*q0.x + q0.y*q0.y + q0.z*q0.z + q0.w*q0.w
           + q1.x*q1.x + q1.y*q1.y + q1.z*q1.z + q1.w*q1.w
           + q2.x*q2.x + q2.y*q2.y + q2.z*q2.z + q2.w*q2.w
           + q3.x*q3.x + q3.y*q3.y + q3.z*q3.z + q3.w*q3.w;
  float arr = ss;
  int sel[4];
  #pragma unroll
  for (int k = 0; k < 4; ++k) {
    float m = arr; int mi = lane;
    #pragma unroll
    for (int o = 32; o > 0; o >>= 1) {
      float om = __shfl_xor(m, o);
      int oi  = __shfl_xor(mi, o);
      if (om > m || (om == m && oi < mi)) { m = om; mi = oi; }
    }
    sel[k] = mi;                 // wave-uniform
    if (lane == mi) arr = -3.0e38f;
  }
  if (lane < 16) {
    float s = vrow[sel[0]*RANK + lane] + vrow[sel[1]*RANK + lane]
            + vrow[sel[2]*RANK + lane] + vrow[sel[3]*RANK + lane];
    vsh[wave][lane] = 0.0625f * s;   // (1/topk in v) * (1/topk routing weight)
  }
  __syncthreads();
  bool on = (lane == sel[0]) | (lane == sel[1]) | (lane == sel[2]) | (lane == sel[3]);
  us8 lo, hi;
  #pragma unroll
  for (int r = 0; r < 8; ++r) lo[r] = on ? f2bf(vsh[wave][r])     : (unsigned short)0;
  #pragma unroll
  for (int r = 0; r < 8; ++r) hi[r] = on ? f2bf(vsh[wave][r + 8]) : (unsigned short)0;
  us8* d = (us8*)(XG + (size_t)t * KTOT + H + lane * RANK);
  d[0] = lo; d[1] = hi;
}

__device__ __forceinline__ void gload_lds16(const void* gsrc, void* ldst) {
  __builtin_amdgcn_global_load_lds(
      (const __attribute__((address_space(1))) unsigned int*)gsrc,
      (__attribute__((address_space(3))) unsigned int*)ldst, 16, 0, 0);
}

// ------------------------------------------------------------------
// Split-precision GEMM: C[8192,1024] = X[8192,2048](f32) @ Aw[1024,2048](f32)^T
// computed as x_hi@A_hi + x_hi@A_lo + x_lo@A_hi in bf16 MFMA (near-fp32 result).
// 128x128 tile, 4 waves (2x2), BK=32, reg-staged hi/lo conversion into LDS.
// ------------------------------------------------------------------
__global__ __launch_bounds__(256, 2) void gemm_split_kernel(
    const float* __restrict__ X, const float* __restrict__ Aw,
    float* __restrict__ C) {
  __shared__ unsigned short As_hi[128 * 32];
  __shared__ unsigned short As_lo[128 * 32];
  __shared__ unsigned short Bs_hi[128 * 32];
  __shared__ unsigned short Bs_lo[128 * 32];
  const int tid = threadIdx.x;
  const int lane = tid & 63, wave = tid >> 6;
  const int wr = wave >> 1, wc = wave & 1;
  const int bm = blockIdx.x, bn = blockIdx.y;

  v4f acc[4][4];
  #pragma unroll
  for (int i = 0; i < 4; ++i)
    #pragma unroll
    for (int j = 0; j < 4; ++j)
      acc[i][j] = (v4f){0.f, 0.f, 0.f, 0.f};

  const float* Xb = X + (size_t)(bm * 128) * H;
  const float* Ab = Aw + (size_t)(bn * 128) * H;
  const int rA = lane & 15;
  const int kk = (lane >> 4) << 3;

  for (int k0 = 0; k0 < H; k0 += 32) {
    #pragma unroll
    for (int rnd = 0; rnd < 4; ++rnd) {
      int u = rnd * 256 + tid;        // 16B unit in the 128x32 fp32 tile
      int r = u >> 3, c4 = (u & 7) << 2;
      float4 xv = *(const float4*)(Xb + (size_t)r * H + k0 + c4);
      float4 av = *(const float4*)(Ab + (size_t)r * H + k0 + c4);
      us4 xh, xl, ah, al;
      split4(xv, xh, xl);
      split4(av, ah, al);
      *(us4*)&As_hi[r * 32 + c4] = xh;
      *(us4*)&As_lo[r * 32 + c4] = xl;
      *(us4*)&Bs_hi[r * 32 + c4] = ah;
      *(us4*)&Bs_lo[r * 32 + c4] = al;
    }
    __syncthreads();
    v8bf ah[4], al[4], bh[4], bl[4];
    #pragma unroll
    for (int i = 0; i < 4; ++i) {
      ah[i] = *(const v8bf*)&As_hi[(wr * 64 + i * 16 + rA) * 32 + kk];
      al[i] = *(const v8bf*)&As_lo[(wr * 64 + i * 16 + rA) * 32 + kk];
    }
    #pragma unroll
    for (int j = 0; j < 4; ++j) {
      bh[j] = *(const v8bf*)&Bs_hi[(wc * 64 + j * 16 + rA) * 32 + kk];
      bl[j] = *(const v8bf*)&Bs_lo[(wc * 64 + j * 16 + rA) * 32 + kk];
    }
    #pragma unroll
    for (int i = 0; i < 4; ++i)
      #pragma unroll
      for (int j = 0; j < 4; ++j) {
        acc[i][j] = __builtin_amdgcn_mfma_f32_16x16x32_bf16(ah[i], bh[j], acc[i][j], 0, 0, 0);
        acc[i][j] = __builtin_amdgcn_mfma_f32_16x16x32_bf16(ah[i], bl[j], acc[i][j], 0, 0, 0);
        acc[i][j] = __builtin_amdgcn_mfma_f32_16x16x32_bf16(al[i], bh[j], acc[i][j], 0, 0, 0);
      }
    __syncthreads();
  }

  const int rowbase = bm * 128 + wr * 64;
  const int colbase = bn * 128 + wc * 64;
  #pragma unroll
  for (int i = 0; i < 4; ++i) {
    int r0 = rowbase + i * 16 + ((lane >> 4) << 2);
    #pragma unroll
    for (int j = 0; j < 4; ++j) {
      int col = colbase + j * 16 + (lane & 15);
      #pragma unroll
      for (int q = 0; q < 4; ++q)
        C[(size_t)(r0 + q) * KG + col] = acc[i][j][q];
    }
  }
}

// C[M,N] = A[M,K](bf16,lda) @ Bt[N,K](bf16,ldb)^T (+bias), fp32 out (ldc).
// 128x128 tile, 4 waves (2x2), 16x16x32 bf16 MFMA, BK=32, global_load_lds staging.
__global__ __launch_bounds__(256, 2) void gemm_bt_kernel(
    const unsigned short* __restrict__ A, const unsigned short* __restrict__ Bt,
    float* __restrict__ C, const float* __restrict__ bias,
    int K, int lda, int ldb, int ldc) {
  __shared__ unsigned short As[128 * 32];
  __shared__ unsigned short Bs[128 * 32];
  const int tid = threadIdx.x;
  const int lane = tid & 63, wave = tid >> 6;
  const int wr = wave >> 1, wc = wave & 1;
  const int bm = blockIdx.x, bn = blockIdx.y;

  v4f acc[4][4];
  #pragma unroll
  for (int i = 0; i < 4; ++i)
    #pragma unroll
    for (int j = 0; j < 4; ++j)
      acc[i][j] = (v4f){0.f, 0.f, 0.f, 0.f};

  const unsigned short* Abase = A + (size_t)(bm * 128) * lda;
  const unsigned short* Bbase = Bt + (size_t)(bn * 128) * ldb;

  const int rA = lane & 15;
  const int kk = (lane >> 4) << 3;   // 0,8,16,24

  for (int k0 = 0; k0 < K; k0 += 32) {
    #pragma unroll
    for (int rnd = 0; rnd < 2; ++rnd) {
      int e = rnd * 256 + tid;           // 16-byte unit index within the 128x32 tile
      int r = e >> 2, c8 = (e & 3) << 3; // row, col-element (8 bf16 per 16B)
      gload_lds16(Abase + (size_t)r * lda + k0 + c8, (char*)As + (size_t)e * 16);
      gload_lds16(Bbase + (size_t)r * ldb + k0 + c8, (char*)Bs + (size_t)e * 16);
    }
    __syncthreads();
    v8bf af[4], bfr[4];
    #pragma unroll
    for (int i = 0; i < 4; ++i)
      af[i] = *(const v8bf*)&As[(wr * 64 + i * 16 + rA) * 32 + kk];
    #pragma unroll
    for (int j = 0; j < 4; ++j)
      bfr[j] = *(const v8bf*)&Bs[(wc * 64 + j * 16 + rA) * 32 + kk];
    #pragma unroll
    for (int i = 0; i < 4; ++i)
      #pragma unroll
      for (int j = 0; j < 4; ++j)
        acc[i][j] = __builtin_amdgcn_mfma_f32_16x16x32_bf16(af[i], bfr[j], acc[i][j], 0, 0, 0);
    __syncthreads();
  }

  const int rowbase = bm * 128 + wr * 64;
  const int colbase = bn * 128 + wc * 64;
  #pragma unroll
  for (int i = 0; i < 4; ++i) {
    int r0 = rowbase + i * 16 + ((lane >> 4) << 2);
    #pragma unroll
    for (int j = 0; j < 4; ++j) {
      int col = colbase + j * 16 + (lane & 15);
      float bv = bias ? bias[col] : 0.f;
      #pragma unroll
      for (int q = 0; q < 4; ++q)
        C[(size_t)(r0 + q) * ldc + col] = acc[i][j][q] + bv;
    }
  }
}

extern "C" void kernel_launch(void* const* d_in, const int* in_sizes, int n_in,
                              void* d_out, int out_size, void* d_ws, size_t ws_size,
                              hipStream_t stream) {
  const float* x    = (const float*)d_in[0];
  const float* A    = (const float*)d_in[1];
  const float* Bb   = (const float*)d_in[2];
  const float* W    = (const float*)d_in[3];
  const float* bias = (const float*)d_in[4];
  float* out = (float*)d_out;

  char* ws = (char*)d_ws;
  // layout: XG bf16 [8192][3072] (48M) | WB bf16 [2048][3072] (12M) | vecs f32 [8192][1024] (32M)
  unsigned short* XG = (unsigned short*)ws;
  unsigned short* WB = (unsigned short*)(ws + (size_t)48 * 1024 * 1024);
  float* vecs        = (float*)(ws + (size_t)60 * 1024 * 1024);

  // casts (x hi-part for gemm2's base block; W and B into WB)
  cast2048_kernel<<<TOKENS, 256, 0, stream>>>(x, XG, KTOT);      // 8192 rows
  cast2048_kernel<<<JDIM, 256, 0, stream>>>(W, WB, KTOT);        // 2048 rows
  cast_b_kernel<<<512, 256, 0, stream>>>(Bb, WB);

  // vecs = x @ A^T in near-fp32 precision (split bf16), M=8192 N=1024 K=2048
  gemm_split_kernel<<<dim3(TOKENS / 128, KG / 128), 256, 0, stream>>>(x, A, vecs);

  // routing -> G block of XG
  route_kernel<<<TOKENS / 4, 256, 0, stream>>>(vecs, XG);

  // out = [Xb|G] @ [Wb|Bt]^T + bias   (M=8192, N=2048, K=3072)
  gemm_bt_kernel<<<dim3(TOKENS / 128, JDIM / 128), 256, 0, stream>>>(
      XG, WB, out, bias, KTOT, KTOT, KTOT, 2048);
}

// Round 3
// 264.694 us; speedup vs baseline: 1.3752x; 1.3752x over previous
//
#include <hip/hip_runtime.h>
#include <hip/hip_bf16.h>
#include <stdint.h>

// Shapes (fixed for this problem)
#define TOKENS 8192   // b*s = 4*2048
#define H 2048
#define JDIM 2048
#define NADAPT 64
#define RANK 16
#define KG 1024       // NADAPT*RANK
#define KTOT 3072     // H + KG

typedef __bf16 v8bf __attribute__((ext_vector_type(8)));
typedef float v4f __attribute__((ext_vector_type(4)));
typedef unsigned short us8 __attribute__((ext_vector_type(8)));
typedef unsigned short us4 __attribute__((ext_vector_type(4)));

__device__ __forceinline__ unsigned short f2bf(float f) {
  union { __bf16 b; unsigned short u; } c; c.b = (__bf16)f; return c.u;
}
__device__ __forceinline__ float bf2f(unsigned short u) {
  union { unsigned int u; float f; } c; c.u = ((unsigned int)u) << 16; return c.f;
}

__device__ __forceinline__ us8 pack8(float4 a, float4 b) {
  us8 r;
  r[0]=f2bf(a.x); r[1]=f2bf(a.y); r[2]=f2bf(a.z); r[3]=f2bf(a.w);
  r[4]=f2bf(b.x); r[5]=f2bf(b.y); r[6]=f2bf(b.z); r[7]=f2bf(b.w);
  return r;
}

__device__ __forceinline__ void split8(float4 a, float4 b, us8& h, us8& l) {
  float v[8] = {a.x, a.y, a.z, a.w, b.x, b.y, b.z, b.w};
  #pragma unroll
  for (int i = 0; i < 8; ++i) {
    h[i] = f2bf(v[i]);
    l[i] = f2bf(v[i] - bf2f(h[i]));
  }
}

// x fp32 [8192][2048] -> hi bf16 into XG (stride KTOT), lo bf16 into XLO (stride 2048).
__global__ void cast_x_split_kernel(const float* __restrict__ x,
                                    unsigned short* __restrict__ XG,
                                    unsigned short* __restrict__ XLO) {
  int idx = blockIdx.x * 256 + threadIdx.x;
  int row = idx >> 8;
  int cg  = idx & 255;
  const float4* s = (const float4*)(x + ((size_t)row << 11) + ((size_t)cg << 3));
  float4 a = s[0], b = s[1];
  us8 h, l;
  split8(a, b, h, l);
  *(us8*)(XG  + (size_t)row * KTOT + ((size_t)cg << 3)) = h;
  *(us8*)(XLO + (size_t)row * H    + ((size_t)cg << 3)) = l;
}

// A fp32 [1024][2048] -> Ahi, Alo bf16 [1024][2048].
__global__ void cast_a_split_kernel(const float* __restrict__ A,
                                    unsigned short* __restrict__ Ahi,
                                    unsigned short* __restrict__ Alo) {
  int idx = blockIdx.x * 256 + threadIdx.x;
  int row = idx >> 8;
  int cg  = idx & 255;
  const float4* s = (const float4*)(A + ((size_t)row << 11) + ((size_t)cg << 3));
  float4 a = s[0], b = s[1];
  us8 h, l;
  split8(a, b, h, l);
  *(us8*)(Ahi + (size_t)row * H + ((size_t)cg << 3)) = h;
  *(us8*)(Alo + (size_t)row * H + ((size_t)cg << 3)) = l;
}

// fp32 [rows][2048] -> bf16 [rows][dstld] (fills cols 0..2047).
__global__ void cast2048_kernel(const float* __restrict__ src,
                                unsigned short* __restrict__ dst, int dstld) {
  int idx = blockIdx.x * 256 + threadIdx.x;
  int row = idx >> 8;
  int cg  = idx & 255;
  const float4* s = (const float4*)(src + ((size_t)row << 11) + ((size_t)cg << 3));
  float4 a = s[0], b = s[1];
  *(us8*)(dst + (size_t)row * dstld + ((size_t)cg << 3)) = pack8(a, b);
}

// B [64][2048][16] fp32 -> WB[j][2048 + a*16 + r] bf16. One thread per (a,j).
__global__ void cast_b_kernel(const float* __restrict__ Bsrc,
                              unsigned short* __restrict__ WB) {
  int idx = blockIdx.x * 256 + threadIdx.x;   // 131072 total
  int a = idx >> 11, j = idx & 2047;
  const float4* s = (const float4*)(Bsrc + (((size_t)a << 11) + j) * RANK);
  float4 f0 = s[0], f1 = s[1], f2 = s[2], f3 = s[3];
  us8* d = (us8*)(WB + (size_t)j * KTOT + H + a * RANK);
  d[0] = pack8(f0, f1);
  d[1] = pack8(f2, f3);
}

// Per token: arrows = sumsq over r, top-4 adapters, G row = routes*v.
// One wave per token, 4 tokens/block.
__global__ void route_kernel(const float* __restrict__ vecs,
                             unsigned short* __restrict__ XG) {
  __shared__ float vsh[4][16];
  int wave = threadIdx.x >> 6, lane = threadIdx.x & 63;
  int t = blockIdx.x * 4 + wave;
  const float* vrow = vecs + (size_t)t * KG;
  const float4* vp = (const float4*)(vrow + lane * RANK);
  float4 q0 = vp[0], q1 = vp[1], q2 = vp[2], q3 = vp[3];
  float ss = q0.x*q0.x + q0.y*q0.y + q0.z*q0.z + q0.w*q0.w
           + q1.x*q1.x + q1.y*q1.y + q1.z*q1.z + q1.w*q1.w
           + q2.x*q2.x + q2.y*q2.y + q2.z*q2.z + q2.w*q2.w
           + q3.x*q3.x + q3.y*q3.y + q3.z*q3.z + q3.w*q3.w;
  float arr = ss;
  int sel[4];
  #pragma unroll
  for (int k = 0; k < 4; ++k) {
    float m = arr; int mi = lane;
    #pragma unroll
    for (int o = 32; o > 0; o >>= 1) {
      float om = __shfl_xor(m, o);
      int oi  = __shfl_xor(mi, o);
      if (om > m || (om == m && oi < mi)) { m = om; mi = oi; }
    }
    sel[k] = mi;                 // wave-uniform
    if (lane == mi) arr = -3.0e38f;
  }
  if (lane < 16) {
    float s = vrow[sel[0]*RANK + lane] + vrow[sel[1]*RANK + lane]
            + vrow[sel[2]*RANK + lane] + vrow[sel[3]*RANK + lane];
    vsh[wave][lane] = 0.0625f * s;   // (1/topk in v) * (1/topk routing weight)
  }
  __syncthreads();
  bool on = (lane == sel[0]) | (lane == sel[1]) | (lane == sel[2]) | (lane == sel[3]);
  us8 lo, hi;
  #pragma unroll
  for (int r = 0; r < 8; ++r) lo[r] = on ? f2bf(vsh[wave][r])     : (unsigned short)0;
  #pragma unroll
  for (int r = 0; r < 8; ++r) hi[r] = on ? f2bf(vsh[wave][r + 8]) : (unsigned short)0;
  us8* d = (us8*)(XG + (size_t)t * KTOT + H + lane * RANK);
  d[0] = lo; d[1] = hi;
}

__device__ __forceinline__ void gload_lds16(const void* gsrc, void* ldst) {
  __builtin_amdgcn_global_load_lds(
      (const __attribute__((address_space(1))) unsigned int*)gsrc,
      (__attribute__((address_space(3))) unsigned int*)ldst, 16, 0, 0);
}

// ------------------------------------------------------------------
// GEMM1 (pre-split): vecs[8192,1024] = Xhi@Ahi^T + Xhi@Alo^T + Xlo@Ahi^T, all bf16.
// 128x128 tile, 4 waves (2x2), BK=32, global_load_lds staging, 48 MFMA / K-step.
// ------------------------------------------------------------------
__global__ __launch_bounds__(256, 2) void gemm1_kernel(
    const unsigned short* __restrict__ Xhi,   // lda KTOT
    const unsigned short* __restrict__ Xlo,   // lda H
    const unsigned short* __restrict__ Ahi,   // ldb H
    const unsigned short* __restrict__ Alo,   // ldb H
    float* __restrict__ C) {                  // ldc KG
  __shared__ unsigned short AsH[128 * 32];
  __shared__ unsigned short AsL[128 * 32];
  __shared__ unsigned short BsH[128 * 32];
  __shared__ unsigned short BsL[128 * 32];
  const int tid = threadIdx.x;
  const int lane = tid & 63, wave = tid >> 6;
  const int wr = wave >> 1, wc = wave & 1;
  const int bm = blockIdx.x, bn = blockIdx.y;

  v4f acc[4][4];
  #pragma unroll
  for (int i = 0; i < 4; ++i)
    #pragma unroll
    for (int j = 0; j < 4; ++j)
      acc[i][j] = (v4f){0.f, 0.f, 0.f, 0.f};

  const unsigned short* XhiB = Xhi + (size_t)(bm * 128) * KTOT;
  const unsigned short* XloB = Xlo + (size_t)(bm * 128) * H;
  const unsigned short* AhiB = Ahi + (size_t)(bn * 128) * H;
  const unsigned short* AloB = Alo + (size_t)(bn * 128) * H;

  const int rA = lane & 15;
  const int kk = (lane >> 4) << 3;   // 0,8,16,24

  for (int k0 = 0; k0 < H; k0 += 32) {
    #pragma unroll
    for (int rnd = 0; rnd < 2; ++rnd) {
      int e = rnd * 256 + tid;           // 16B unit within a 128x32 bf16 tile
      int r = e >> 2, c8 = (e & 3) << 3;
      gload_lds16(XhiB + (size_t)r * KTOT + k0 + c8, (char*)AsH + (size_t)e * 16);
      gload_lds16(XloB + (size_t)r * H    + k0 + c8, (char*)AsL + (size_t)e * 16);
      gload_lds16(AhiB + (size_t)r * H    + k0 + c8, (char*)BsH + (size_t)e * 16);
      gload_lds16(AloB + (size_t)r * H    + k0 + c8, (char*)BsL + (size_t)e * 16);
    }
    __syncthreads();
    v8bf ah[4], al[4], bh[4], bl[4];
    #pragma unroll
    for (int i = 0; i < 4; ++i) {
      ah[i] = *(const v8bf*)&AsH[(wr * 64 + i * 16 + rA) * 32 + kk];
      al[i] = *(const v8bf*)&AsL[(wr * 64 + i * 16 + rA) * 32 + kk];
    }
    #pragma unroll
    for (int j = 0; j < 4; ++j) {
      bh[j] = *(const v8bf*)&BsH[(wc * 64 + j * 16 + rA) * 32 + kk];
      bl[j] = *(const v8bf*)&BsL[(wc * 64 + j * 16 + rA) * 32 + kk];
    }
    #pragma unroll
    for (int i = 0; i < 4; ++i)
      #pragma unroll
      for (int j = 0; j < 4; ++j) {
        acc[i][j] = __builtin_amdgcn_mfma_f32_16x16x32_bf16(ah[i], bh[j], acc[i][j], 0, 0, 0);
        acc[i][j] = __builtin_amdgcn_mfma_f32_16x16x32_bf16(ah[i], bl[j], acc[i][j], 0, 0, 0);
        acc[i][j] = __builtin_amdgcn_mfma_f32_16x16x32_bf16(al[i], bh[j], acc[i][j], 0, 0, 0);
      }
    __syncthreads();
  }

  const int rowbase = bm * 128 + wr * 64;
  const int colbase = bn * 128 + wc * 64;
  #pragma unroll
  for (int i = 0; i < 4; ++i) {
    int r0 = rowbase + i * 16 + ((lane >> 4) << 2);
    #pragma unroll
    for (int j = 0; j < 4; ++j) {
      int col = colbase + j * 16 + (lane & 15);
      #pragma unroll
      for (int q = 0; q < 4; ++q)
        C[(size_t)(r0 + q) * KG + col] = acc[i][j][q];
    }
  }
}

// C[M,N] = A[M,K](bf16,lda) @ Bt[N,K](bf16,ldb)^T (+bias), fp32 out (ldc).
// 128x128 tile, 4 waves (2x2), 16x16x32 bf16 MFMA, BK=32, global_load_lds staging.
__global__ __launch_bounds__(256, 2) void gemm_bt_kernel(
    const unsigned short* __restrict__ A, const unsigned short* __restrict__ Bt,
    float* __restrict__ C, const float* __restrict__ bias,
    int K, int lda, int ldb, int ldc) {
  __shared__ unsigned short As[128 * 32];
  __shared__ unsigned short Bs[128 * 32];
  const int tid = threadIdx.x;
  const int lane = tid & 63, wave = tid >> 6;
  const int wr = wave >> 1, wc = wave & 1;
  const int bm = blockIdx.x, bn = blockIdx.y;

  v4f acc[4][4];
  #pragma unroll
  for (int i = 0; i < 4; ++i)
    #pragma unroll
    for (int j = 0; j < 4; ++j)
      acc[i][j] = (v4f){0.f, 0.f, 0.f, 0.f};

  const unsigned short* Abase = A + (size_t)(bm * 128) * lda;
  const unsigned short* Bbase = Bt + (size_t)(bn * 128) * ldb;

  const int rA = lane & 15;
  const int kk = (lane >> 4) << 3;   // 0,8,16,24

  for (int k0 = 0; k0 < K; k0 += 32) {
    #pragma unroll
    for (int rnd = 0; rnd < 2; ++rnd) {
      int e = rnd * 256 + tid;           // 16-byte unit index within the 128x32 tile
      int r = e >> 2, c8 = (e & 3) << 3; // row, col-element (8 bf16 per 16B)
      gload_lds16(Abase + (size_t)r * lda + k0 + c8, (char*)As + (size_t)e * 16);
      gload_lds16(Bbase + (size_t)r * ldb + k0 + c8, (char*)Bs + (size_t)e * 16);
    }
    __syncthreads();
    v8bf af[4], bfr[4];
    #pragma unroll
    for (int i = 0; i < 4; ++i)
      af[i] = *(const v8bf*)&As[(wr * 64 + i * 16 + rA) * 32 + kk];
    #pragma unroll
    for (int j = 0; j < 4; ++j)
      bfr[j] = *(const v8bf*)&Bs[(wc * 64 + j * 16 + rA) * 32 + kk];
    #pragma unroll
    for (int i = 0; i < 4; ++i)
      #pragma unroll
      for (int j = 0; j < 4; ++j)
        acc[i][j] = __builtin_amdgcn_mfma_f32_16x16x32_bf16(af[i], bfr[j], acc[i][j], 0, 0, 0);
    __syncthreads();
  }

  const int rowbase = bm * 128 + wr * 64;
  const int colbase = bn * 128 + wc * 64;
  #pragma unroll
  for (int i = 0; i < 4; ++i) {
    int r0 = rowbase + i * 16 + ((lane >> 4) << 2);
    #pragma unroll
    for (int j = 0; j < 4; ++j) {
      int col = colbase + j * 16 + (lane & 15);
      float bv = bias ? bias[col] : 0.f;
      #pragma unroll
      for (int q = 0; q < 4; ++q)
        C[(size_t)(r0 + q) * ldc + col] = acc[i][j][q] + bv;
    }
  }
}

extern "C" void kernel_launch(void* const* d_in, const int* in_sizes, int n_in,
                              void* d_out, int out_size, void* d_ws, size_t ws_size,
                              hipStream_t stream) {
  const float* x    = (const float*)d_in[0];
  const float* A    = (const float*)d_in[1];
  const float* Bb   = (const float*)d_in[2];
  const float* W    = (const float*)d_in[3];
  const float* bias = (const float*)d_in[4];
  float* out = (float*)d_out;

  char* ws = (char*)d_ws;
  // ws layout: XG bf16 [8192][3072] (48M) | WB bf16 [2048][3072] (12M) |
  //            Ahi bf16 [1024][2048] (4M) | Alo bf16 [1024][2048] (4M)   = 68M
  unsigned short* XG  = (unsigned short*)ws;
  unsigned short* WB  = (unsigned short*)(ws + (size_t)48 * 1024 * 1024);
  unsigned short* Ahi = (unsigned short*)(ws + (size_t)60 * 1024 * 1024);
  unsigned short* Alo = (unsigned short*)(ws + (size_t)64 * 1024 * 1024);
  // d_out (64MB fp32) doubles as pre-gemm2 scratch:
  //   lower 32MB: vecs f32 [8192][1024]; upper 32MB: x_lo bf16 [8192][2048].
  // All regions fully rewritten every call; gemm2 overwrites d_out last.
  float* vecs         = (float*)d_out;
  unsigned short* XLO = (unsigned short*)((char*)d_out + (size_t)32 * 1024 * 1024);

  // casts (x -> hi into XG + lo into XLO; A -> hi/lo; W,B -> WB)
  cast_x_split_kernel<<<TOKENS, 256, 0, stream>>>(x, XG, XLO);
  cast_a_split_kernel<<<KG / 1, 256, 0, stream>>>(A, Ahi, Alo);  // 1024 blocks
  cast2048_kernel<<<JDIM, 256, 0, stream>>>(W, WB, KTOT);
  cast_b_kernel<<<512, 256, 0, stream>>>(Bb, WB);

  // vecs = x @ A^T in near-fp32 (3-term bf16 split), M=8192 N=1024 K=2048
  gemm1_kernel<<<dim3(TOKENS / 128, KG / 128), 256, 0, stream>>>(
      XG, XLO, Ahi, Alo, vecs);

  // routing -> G block of XG (reads vecs from d_out lower half)
  route_kernel<<<TOKENS / 4, 256, 0, stream>>>(vecs, XG);

  // out = [Xb|G] @ [Wb|Bt]^T + bias   (M=8192, N=2048, K=3072) — overwrites d_out
  gemm_bt_kernel<<<dim3(TOKENS / 128, JDIM / 128), 256, 0, stream>>>(
      XG, WB, out, bias, KTOT, KTOT, KTOT, 2048);
}

// Round 4
// 246.315 us; speedup vs baseline: 1.4778x; 1.0746x over previous
//
#include <hip/hip_runtime.h>
#include <hip/hip_bf16.h>
#include <stdint.h>

// Shapes (fixed for this problem)
#define TOKENS 8192   // b*s = 4*2048
#define H 2048
#define JDIM 2048
#define NADAPT 64
#define RANK 16
#define KG 1024       // NADAPT*RANK
#define KTOT 3072     // H + KG
#define NT2 48        // gemm2 K-tiles = KTOT/64

typedef __bf16 v8bf __attribute__((ext_vector_type(8)));
typedef float v4f __attribute__((ext_vector_type(4)));
typedef unsigned short us8 __attribute__((ext_vector_type(8)));
typedef unsigned short us4 __attribute__((ext_vector_type(4)));

__device__ __forceinline__ unsigned short f2bf(float f) {
  union { __bf16 b; unsigned short u; } c; c.b = (__bf16)f; return c.u;
}
__device__ __forceinline__ float bf2f(unsigned short u) {
  union { unsigned int u; float f; } c; c.u = ((unsigned int)u) << 16; return c.f;
}

__device__ __forceinline__ us8 pack8(float4 a, float4 b) {
  us8 r;
  r[0]=f2bf(a.x); r[1]=f2bf(a.y); r[2]=f2bf(a.z); r[3]=f2bf(a.w);
  r[4]=f2bf(b.x); r[5]=f2bf(b.y); r[6]=f2bf(b.z); r[7]=f2bf(b.w);
  return r;
}

__device__ __forceinline__ void split8(float4 a, float4 b, us8& h, us8& l) {
  float v[8] = {a.x, a.y, a.z, a.w, b.x, b.y, b.z, b.w};
  #pragma unroll
  for (int i = 0; i < 8; ++i) {
    h[i] = f2bf(v[i]);
    l[i] = f2bf(v[i] - bf2f(h[i]));
  }
}

// x fp32 [8192][2048] -> hi bf16 into XG (stride KTOT), lo bf16 into XLO (stride 2048).
__global__ void cast_x_split_kernel(const float* __restrict__ x,
                                    unsigned short* __restrict__ XG,
                                    unsigned short* __restrict__ XLO) {
  int idx = blockIdx.x * 256 + threadIdx.x;
  int row = idx >> 8;
  int cg  = idx & 255;
  const float4* s = (const float4*)(x + ((size_t)row << 11) + ((size_t)cg << 3));
  float4 a = s[0], b = s[1];
  us8 h, l;
  split8(a, b, h, l);
  *(us8*)(XG  + (size_t)row * KTOT + ((size_t)cg << 3)) = h;
  *(us8*)(XLO + (size_t)row * H    + ((size_t)cg << 3)) = l;
}

// A fp32 [1024][2048] -> Ahi, Alo bf16 [1024][2048].
__global__ void cast_a_split_kernel(const float* __restrict__ A,
                                    unsigned short* __restrict__ Ahi,
                                    unsigned short* __restrict__ Alo) {
  int idx = blockIdx.x * 256 + threadIdx.x;
  int row = idx >> 8;
  int cg  = idx & 255;
  const float4* s = (const float4*)(A + ((size_t)row << 11) + ((size_t)cg << 3));
  float4 a = s[0], b = s[1];
  us8 h, l;
  split8(a, b, h, l);
  *(us8*)(Ahi + (size_t)row * H + ((size_t)cg << 3)) = h;
  *(us8*)(Alo + (size_t)row * H + ((size_t)cg << 3)) = l;
}

// fp32 [rows][2048] -> bf16 [rows][dstld] (fills cols 0..2047).
__global__ void cast2048_kernel(const float* __restrict__ src,
                                unsigned short* __restrict__ dst, int dstld) {
  int idx = blockIdx.x * 256 + threadIdx.x;
  int row = idx >> 8;
  int cg  = idx & 255;
  const float4* s = (const float4*)(src + ((size_t)row << 11) + ((size_t)cg << 3));
  float4 a = s[0], b = s[1];
  *(us8*)(dst + (size_t)row * dstld + ((size_t)cg << 3)) = pack8(a, b);
}

// B [64][2048][16] fp32 -> WB[j][2048 + a*16 + r] bf16. One thread per (a,j).
__global__ void cast_b_kernel(const float* __restrict__ Bsrc,
                              unsigned short* __restrict__ WB) {
  int idx = blockIdx.x * 256 + threadIdx.x;   // 131072 total
  int a = idx >> 11, j = idx & 2047;
  const float4* s = (const float4*)(Bsrc + (((size_t)a << 11) + j) * RANK);
  float4 f0 = s[0], f1 = s[1], f2 = s[2], f3 = s[3];
  us8* d = (us8*)(WB + (size_t)j * KTOT + H + a * RANK);
  d[0] = pack8(f0, f1);
  d[1] = pack8(f2, f3);
}

// Per token: arrows = sumsq over r, top-4 adapters, G row = routes*v.
__global__ void route_kernel(const float* __restrict__ vecs,
                             unsigned short* __restrict__ XG) {
  __shared__ float vsh[4][16];
  int wave = threadIdx.x >> 6, lane = threadIdx.x & 63;
  int t = blockIdx.x * 4 + wave;
  const float* vrow = vecs + (size_t)t * KG;
  const float4* vp = (const float4*)(vrow + lane * RANK);
  float4 q0 = vp[0], q1 = vp[1], q2 = vp[2], q3 = vp[3];
  float ss = q0.x*q0.x + q0.y*q0.y + q0.z*q0.z + q0.w*q0.w
           + q1.x*q1.x + q1.y*q1.y + q1.z*q1.z + q1.w*q1.w
           + q2.x*q2.x + q2.y*q2.y + q2.z*q2.z + q2.w*q2.w
           + q3.x*q3.x + q3.y*q3.y + q3.z*q3.z + q3.w*q3.w;
  float arr = ss;
  int sel[4];
  #pragma unroll
  for (int k = 0; k < 4; ++k) {
    float m = arr; int mi = lane;
    #pragma unroll
    for (int o = 32; o > 0; o >>= 1) {
      float om = __shfl_xor(m, o);
      int oi  = __shfl_xor(mi, o);
      if (om > m || (om == m && oi < mi)) { m = om; mi = oi; }
    }
    sel[k] = mi;                 // wave-uniform
    if (lane == mi) arr = -3.0e38f;
  }
  if (lane < 16) {
    float s = vrow[sel[0]*RANK + lane] + vrow[sel[1]*RANK + lane]
            + vrow[sel[2]*RANK + lane] + vrow[sel[3]*RANK + lane];
    vsh[wave][lane] = 0.0625f * s;
  }
  __syncthreads();
  bool on = (lane == sel[0]) | (lane == sel[1]) | (lane == sel[2]) | (lane == sel[3]);
  us8 lo, hi;
  #pragma unroll
  for (int r = 0; r < 8; ++r) lo[r] = on ? f2bf(vsh[wave][r])     : (unsigned short)0;
  #pragma unroll
  for (int r = 0; r < 8; ++r) hi[r] = on ? f2bf(vsh[wave][r + 8]) : (unsigned short)0;
  us8* d = (us8*)(XG + (size_t)t * KTOT + H + lane * RANK);
  d[0] = lo; d[1] = hi;
}

__device__ __forceinline__ void gload_lds16(const void* gsrc, void* ldst) {
  __builtin_amdgcn_global_load_lds(
      (const __attribute__((address_space(1))) unsigned int*)gsrc,
      (__attribute__((address_space(3))) unsigned int*)ldst, 16, 0, 0);
}

// ------------------------------------------------------------------
// GEMM1 (pre-split): vecs[8192,1024] = Xhi@Ahi^T + Xhi@Alo^T + Xlo@Ahi^T, all bf16.
// 128x128 tile, 4 waves (2x2), BK=32, global_load_lds staging, 48 MFMA / K-step.
// ------------------------------------------------------------------
__global__ __launch_bounds__(256, 2) void gemm1_kernel(
    const unsigned short* __restrict__ Xhi,   // lda KTOT
    const unsigned short* __restrict__ Xlo,   // lda H
    const unsigned short* __restrict__ Ahi,   // ldb H
    const unsigned short* __restrict__ Alo,   // ldb H
    float* __restrict__ C) {                  // ldc KG
  __shared__ unsigned short AsH[128 * 32];
  __shared__ unsigned short AsL[128 * 32];
  __shared__ unsigned short BsH[128 * 32];
  __shared__ unsigned short BsL[128 * 32];
  const int tid = threadIdx.x;
  const int lane = tid & 63, wave = tid >> 6;
  const int wr = wave >> 1, wc = wave & 1;
  const int bm = blockIdx.x, bn = blockIdx.y;

  v4f acc[4][4];
  #pragma unroll
  for (int i = 0; i < 4; ++i)
    #pragma unroll
    for (int j = 0; j < 4; ++j)
      acc[i][j] = (v4f){0.f, 0.f, 0.f, 0.f};

  const unsigned short* XhiB = Xhi + (size_t)(bm * 128) * KTOT;
  const unsigned short* XloB = Xlo + (size_t)(bm * 128) * H;
  const unsigned short* AhiB = Ahi + (size_t)(bn * 128) * H;
  const unsigned short* AloB = Alo + (size_t)(bn * 128) * H;

  const int rA = lane & 15;
  const int kk = (lane >> 4) << 3;   // 0,8,16,24

  for (int k0 = 0; k0 < H; k0 += 32) {
    #pragma unroll
    for (int rnd = 0; rnd < 2; ++rnd) {
      int e = rnd * 256 + tid;           // 16B unit within a 128x32 bf16 tile
      int r = e >> 2, c8 = (e & 3) << 3;
      gload_lds16(XhiB + (size_t)r * KTOT + k0 + c8, (char*)AsH + (size_t)e * 16);
      gload_lds16(XloB + (size_t)r * H    + k0 + c8, (char*)AsL + (size_t)e * 16);
      gload_lds16(AhiB + (size_t)r * H    + k0 + c8, (char*)BsH + (size_t)e * 16);
      gload_lds16(AloB + (size_t)r * H    + k0 + c8, (char*)BsL + (size_t)e * 16);
    }
    __syncthreads();
    v8bf ah[4], al[4], bh[4], bl[4];
    #pragma unroll
    for (int i = 0; i < 4; ++i) {
      ah[i] = *(const v8bf*)&AsH[(wr * 64 + i * 16 + rA) * 32 + kk];
      al[i] = *(const v8bf*)&AsL[(wr * 64 + i * 16 + rA) * 32 + kk];
    }
    #pragma unroll
    for (int j = 0; j < 4; ++j) {
      bh[j] = *(const v8bf*)&BsH[(wc * 64 + j * 16 + rA) * 32 + kk];
      bl[j] = *(const v8bf*)&BsL[(wc * 64 + j * 16 + rA) * 32 + kk];
    }
    #pragma unroll
    for (int i = 0; i < 4; ++i)
      #pragma unroll
      for (int j = 0; j < 4; ++j) {
        acc[i][j] = __builtin_amdgcn_mfma_f32_16x16x32_bf16(ah[i], bh[j], acc[i][j], 0, 0, 0);
        acc[i][j] = __builtin_amdgcn_mfma_f32_16x16x32_bf16(ah[i], bl[j], acc[i][j], 0, 0, 0);
        acc[i][j] = __builtin_amdgcn_mfma_f32_16x16x32_bf16(al[i], bh[j], acc[i][j], 0, 0, 0);
      }
    __syncthreads();
  }

  const int rowbase = bm * 128 + wr * 64;
  const int colbase = bn * 128 + wc * 64;
  #pragma unroll
  for (int i = 0; i < 4; ++i) {
    int r0 = rowbase + i * 16 + ((lane >> 4) << 2);
    #pragma unroll
    for (int j = 0; j < 4; ++j) {
      int col = colbase + j * 16 + (lane & 15);
      #pragma unroll
      for (int q = 0; q < 4; ++q)
        C[(size_t)(r0 + q) * KG + col] = acc[i][j][q];
    }
  }
}

// ------------------------------------------------------------------
// GEMM2: out[8192,2048] = XG[8192,3072]@WB[2048,3072]^T + bias.
// 256x256 tile, BK=64, 8 waves (2Mx4N, per-wave 128x64), 8-phase schedule:
// K-half LDS regions (16KB each, x2 dbuf = 128KB), counted vmcnt(8), setprio,
// 4-way-max bank swizzle (byte ^= (row&3)<<4 on both stage-src and ds_read).
// ------------------------------------------------------------------
#define BAR() asm volatile("s_waitcnt lgkmcnt(0)\n\ts_barrier" ::: "memory")
#define VM8() asm volatile("s_waitcnt vmcnt(8)" ::: "memory")

#define STAGE(regionUS, panel, kelem) do {                                        \
  gload_lds16((panel) + aoff0 + (kelem), (char*)(regionUS) + tid * 16);           \
  gload_lds16((panel) + aoff1 + (kelem), (char*)(regionUS) + 8192 + tid * 16);    \
} while (0)

#define PHASE(mh, RAr, RBr, ISSUE, DOVM) do {                                     \
  if ((mh) == 0) {                                                                \
    _Pragma("unroll")                                                             \
    for (int j = 0; j < 4; ++j)                                                   \
      bfr[j] = *(const v8bf*)((const char*)(RBr) + bbyte + j * 1024);             \
  }                                                                               \
  _Pragma("unroll")                                                               \
  for (int i = 0; i < 4; ++i)                                                     \
    af[i] = *(const v8bf*)((const char*)(RAr) + abyte + ((mh)*4 + i) * 1024);     \
  ISSUE;                                                                          \
  BAR();                                                                          \
  __builtin_amdgcn_s_setprio(1);                                                  \
  _Pragma("unroll")                                                               \
  for (int i = 0; i < 4; ++i)                                                     \
    _Pragma("unroll")                                                             \
    for (int j = 0; j < 4; ++j)                                                   \
      acc[(mh)*4 + i][j] = __builtin_amdgcn_mfma_f32_16x16x32_bf16(               \
          af[i], bfr[j], acc[(mh)*4 + i][j], 0, 0, 0);                            \
  __builtin_amdgcn_s_setprio(0);                                                  \
  DOVM;                                                                           \
  BAR();                                                                          \
} while (0)

__global__ __launch_bounds__(512, 1) void gemm2_8ph_kernel(
    const unsigned short* __restrict__ Xg, const unsigned short* __restrict__ Wb,
    float* __restrict__ C, const float* __restrict__ bias) {
  __shared__ unsigned short lds[65536];   // 128 KB
  const int tid = threadIdx.x;
  const int lane = tid & 63, wid = tid >> 6;
  const int wr = wid >> 2, wc = wid & 3;
  const int rA = lane & 15, grp = lane >> 4;
  const int grpx = (grp ^ (rA & 3)) << 4;          // swizzled 16B slot (byte)

  const int bid = blockIdx.x;
  const int bn = bid & 7, bm = bid >> 3;           // each XCD owns one bn column

  const unsigned short* Ap = Xg + (size_t)(bm * 256) * KTOT;
  const unsigned short* Bp = Wb + (size_t)(bn * 256) * KTOT;

  // staging addresses: LDS chunk u = l*512+tid at byte u*16; source row u>>2,
  // swizzled 8-elem slot ((u&3)^((u>>2)&3))
  const int srow = tid >> 2;
  const int scol = ((tid & 3) ^ ((tid >> 2) & 3)) << 3;
  const size_t aoff0 = (size_t)srow * KTOT + scol;
  const size_t aoff1 = (size_t)(srow + 128) * KTOT + scol;

  // LDS regions (ushort offsets): buf b at b*32768; A-k0 +0, A-k1 +8192,
  // B-k0 +16384, B-k1 +24576
  unsigned short* A0k0 = lds;
  unsigned short* A0k1 = lds + 8192;
  unsigned short* B0k0 = lds + 16384;
  unsigned short* B0k1 = lds + 24576;
  unsigned short* A1k0 = lds + 32768;
  unsigned short* A1k1 = lds + 40960;
  unsigned short* B1k0 = lds + 49152;
  unsigned short* B1k1 = lds + 57344;

  const int abyte = (wr * 128 + rA) * 64 + grpx;   // + (mi*16)*64 per fragment
  const int bbyte = (wc * 64 + rA) * 64 + grpx;    // + (nj*16)*64

  v4f acc[8][4];
  #pragma unroll
  for (int i = 0; i < 8; ++i)
    #pragma unroll
    for (int j = 0; j < 4; ++j)
      acc[i][j] = (v4f){0.f, 0.f, 0.f, 0.f};
  v8bf af[4], bfr[4];

  // prologue: tile0 (4 halves) + tile1 k0 halves; wait for tile0-k0.
  STAGE(A0k0, Ap, 0);
  STAGE(B0k0, Bp, 0);
  STAGE(A0k1, Ap, 32);
  STAGE(B0k1, Bp, 32);
  STAGE(A1k0, Ap, 64);
  STAGE(B1k0, Bp, 64);
  VM8();
  BAR();

  #pragma unroll 1
  for (int t = 0; t < NT2; t += 2) {
    const int k1a = (t + 1) * 64 + 32;                          // k1(t+1)
    const int k0a = (t + 2 < NT2 ? t + 2 : NT2 - 1) * 64;       // k0(t+2)
    const int k1b = (t + 2 < NT2 ? t + 2 : NT2 - 1) * 64 + 32;  // k1(t+2)
    const int k0b = (t + 3 < NT2 ? t + 3 : NT2 - 1) * 64;       // k0(t+3)
    // tile t (buf0)
    PHASE(0, A0k0, B0k0, STAGE(A1k1, Ap, k1a), ((void)0));
    PHASE(1, A0k0, B0k0, STAGE(B1k1, Bp, k1a), VM8());
    PHASE(0, A0k1, B0k1, STAGE(A0k0, Ap, k0a), ((void)0));
    PHASE(1, A0k1, B0k1, STAGE(B0k0, Bp, k0a), VM8());
    // tile t+1 (buf1)
    PHASE(0, A1k0, B1k0, STAGE(A0k1, Ap, k1b), ((void)0));
    PHASE(1, A1k0, B1k0, STAGE(B0k1, Bp, k1b), VM8());
    PHASE(0, A1k1, B1k1, STAGE(A1k0, Ap, k0b), ((void)0));
    PHASE(1, A1k1, B1k1, STAGE(B1k0, Bp, k0b), VM8());
  }

  // epilogue
  const int row0 = bm * 256 + wr * 128 + (grp << 2);
  const int col0 = bn * 256 + wc * 64 + rA;
  float bv[4];
  #pragma unroll
  for (int j = 0; j < 4; ++j) bv[j] = bias[col0 + j * 16];
  #pragma unroll
  for (int mi = 0; mi < 8; ++mi)
    #pragma unroll
    for (int j = 0; j < 4; ++j)
      #pragma unroll
      for (int q = 0; q < 4; ++q)
        C[(size_t)(row0 + mi * 16 + q) * JDIM + col0 + j * 16] = acc[mi][j][q] + bv[j];
}

extern "C" void kernel_launch(void* const* d_in, const int* in_sizes, int n_in,
                              void* d_out, int out_size, void* d_ws, size_t ws_size,
                              hipStream_t stream) {
  const float* x    = (const float*)d_in[0];
  const float* A    = (const float*)d_in[1];
  const float* Bb   = (const float*)d_in[2];
  const float* W    = (const float*)d_in[3];
  const float* bias = (const float*)d_in[4];
  float* out = (float*)d_out;

  char* ws = (char*)d_ws;
  // ws layout: XG bf16 [8192][3072] (48M) | WB bf16 [2048][3072] (12M) |
  //            Ahi bf16 [1024][2048] (4M) | Alo bf16 [1024][2048] (4M)   = 68M
  unsigned short* XG  = (unsigned short*)ws;
  unsigned short* WB  = (unsigned short*)(ws + (size_t)48 * 1024 * 1024);
  unsigned short* Ahi = (unsigned short*)(ws + (size_t)60 * 1024 * 1024);
  unsigned short* Alo = (unsigned short*)(ws + (size_t)64 * 1024 * 1024);
  // d_out doubles as pre-gemm2 scratch: lower 32MB vecs f32, upper 32MB x_lo bf16.
  float* vecs         = (float*)d_out;
  unsigned short* XLO = (unsigned short*)((char*)d_out + (size_t)32 * 1024 * 1024);

  cast_x_split_kernel<<<TOKENS, 256, 0, stream>>>(x, XG, XLO);
  cast_a_split_kernel<<<KG / 1, 256, 0, stream>>>(A, Ahi, Alo);
  cast2048_kernel<<<JDIM, 256, 0, stream>>>(W, WB, KTOT);
  cast_b_kernel<<<512, 256, 0, stream>>>(Bb, WB);

  // vecs = x @ A^T in near-fp32 (3-term bf16 split), M=8192 N=1024 K=2048
  gemm1_kernel<<<dim3(TOKENS / 128, KG / 128), 256, 0, stream>>>(
      XG, XLO, Ahi, Alo, vecs);

  // routing -> G block of XG
  route_kernel<<<TOKENS / 4, 256, 0, stream>>>(vecs, XG);

  // out = [Xb|G] @ [Wb|Bt]^T + bias   (M=8192, N=2048, K=3072), 8-phase 256² tile
  gemm2_8ph_kernel<<<256, 512, 0, stream>>>(XG, WB, out, bias);
}

// Round 5
// 232.090 us; speedup vs baseline: 1.5684x; 1.0613x over previous
//
#include <hip/hip_runtime.h>
#include <hip/hip_bf16.h>
#include <stdint.h>

// Shapes (fixed for this problem)
#define TOKENS 8192   // b*s = 4*2048
#define H 2048
#define JDIM 2048
#define NADAPT 64
#define RANK 16
#define KG 1024       // NADAPT*RANK
#define KTOT 3072     // H + KG
#define NT2 48        // gemm2 K-tiles = KTOT/64

typedef __bf16 v8bf __attribute__((ext_vector_type(8)));
typedef float v4f __attribute__((ext_vector_type(4)));
typedef unsigned short us8 __attribute__((ext_vector_type(8)));
typedef unsigned short us4 __attribute__((ext_vector_type(4)));

__device__ __forceinline__ unsigned short f2bf(float f) {
  union { __bf16 b; unsigned short u; } c; c.b = (__bf16)f; return c.u;
}
__device__ __forceinline__ float bf2f(unsigned short u) {
  union { unsigned int u; float f; } c; c.u = ((unsigned int)u) << 16; return c.f;
}

__device__ __forceinline__ us8 pack8(float4 a, float4 b) {
  us8 r;
  r[0]=f2bf(a.x); r[1]=f2bf(a.y); r[2]=f2bf(a.z); r[3]=f2bf(a.w);
  r[4]=f2bf(b.x); r[5]=f2bf(b.y); r[6]=f2bf(b.z); r[7]=f2bf(b.w);
  return r;
}

__device__ __forceinline__ void split8(float4 a, float4 b, us8& h, us8& l) {
  float v[8] = {a.x, a.y, a.z, a.w, b.x, b.y, b.z, b.w};
  #pragma unroll
  for (int i = 0; i < 8; ++i) {
    h[i] = f2bf(v[i]);
    l[i] = f2bf(v[i] - bf2f(h[i]));
  }
}

// x fp32 [8192][2048] -> hi bf16 into XG (stride KTOT), lo bf16 into XLO (stride 2048).
__global__ void cast_x_split_kernel(const float* __restrict__ x,
                                    unsigned short* __restrict__ XG,
                                    unsigned short* __restrict__ XLO) {
  int idx = blockIdx.x * 256 + threadIdx.x;
  int row = idx >> 8;
  int cg  = idx & 255;
  const float4* s = (const float4*)(x + ((size_t)row << 11) + ((size_t)cg << 3));
  float4 a = s[0], b = s[1];
  us8 h, l;
  split8(a, b, h, l);
  *(us8*)(XG  + (size_t)row * KTOT + ((size_t)cg << 3)) = h;
  *(us8*)(XLO + (size_t)row * H    + ((size_t)cg << 3)) = l;
}

// A fp32 [1024][2048] -> Ahi, Alo bf16 [1024][2048].
__global__ void cast_a_split_kernel(const float* __restrict__ A,
                                    unsigned short* __restrict__ Ahi,
                                    unsigned short* __restrict__ Alo) {
  int idx = blockIdx.x * 256 + threadIdx.x;
  int row = idx >> 8;
  int cg  = idx & 255;
  const float4* s = (const float4*)(A + ((size_t)row << 11) + ((size_t)cg << 3));
  float4 a = s[0], b = s[1];
  us8 h, l;
  split8(a, b, h, l);
  *(us8*)(Ahi + (size_t)row * H + ((size_t)cg << 3)) = h;
  *(us8*)(Alo + (size_t)row * H + ((size_t)cg << 3)) = l;
}

// fp32 [rows][2048] -> bf16 [rows][dstld] (fills cols 0..2047).
__global__ void cast2048_kernel(const float* __restrict__ src,
                                unsigned short* __restrict__ dst, int dstld) {
  int idx = blockIdx.x * 256 + threadIdx.x;
  int row = idx >> 8;
  int cg  = idx & 255;
  const float4* s = (const float4*)(src + ((size_t)row << 11) + ((size_t)cg << 3));
  float4 a = s[0], b = s[1];
  *(us8*)(dst + (size_t)row * dstld + ((size_t)cg << 3)) = pack8(a, b);
}

// B [64][2048][16] fp32 -> WB[j][2048 + a*16 + r] bf16. One thread per (a,j).
__global__ void cast_b_kernel(const float* __restrict__ Bsrc,
                              unsigned short* __restrict__ WB) {
  int idx = blockIdx.x * 256 + threadIdx.x;   // 131072 total
  int a = idx >> 11, j = idx & 2047;
  const float4* s = (const float4*)(Bsrc + (((size_t)a << 11) + j) * RANK);
  float4 f0 = s[0], f1 = s[1], f2 = s[2], f3 = s[3];
  us8* d = (us8*)(WB + (size_t)j * KTOT + H + a * RANK);
  d[0] = pack8(f0, f1);
  d[1] = pack8(f2, f3);
}

// Per token: arrows = sumsq over r, top-4 adapters, G row = routes*v.
__global__ void route_kernel(const float* __restrict__ vecs,
                             unsigned short* __restrict__ XG) {
  __shared__ float vsh[4][16];
  int wave = threadIdx.x >> 6, lane = threadIdx.x & 63;
  int t = blockIdx.x * 4 + wave;
  const float* vrow = vecs + (size_t)t * KG;
  const float4* vp = (const float4*)(vrow + lane * RANK);
  float4 q0 = vp[0], q1 = vp[1], q2 = vp[2], q3 = vp[3];
  float ss = q0.x*q0.x + q0.y*q0.y + q0.z*q0.z + q0.w*q0.w
           + q1.x*q1.x + q1.y*q1.y + q1.z*q1.z + q1.w*q1.w
           + q2.x*q2.x + q2.y*q2.y + q2.z*q2.z + q2.w*q2.w
           + q3.x*q3.x + q3.y*q3.y + q3.z*q3.z + q3.w*q3.w;
  float arr = ss;
  int sel[4];
  #pragma unroll
  for (int k = 0; k < 4; ++k) {
    float m = arr; int mi = lane;
    #pragma unroll
    for (int o = 32; o > 0; o >>= 1) {
      float om = __shfl_xor(m, o);
      int oi  = __shfl_xor(mi, o);
      if (om > m || (om == m && oi < mi)) { m = om; mi = oi; }
    }
    sel[k] = mi;                 // wave-uniform
    if (lane == mi) arr = -3.0e38f;
  }
  if (lane < 16) {
    float s = vrow[sel[0]*RANK + lane] + vrow[sel[1]*RANK + lane]
            + vrow[sel[2]*RANK + lane] + vrow[sel[3]*RANK + lane];
    vsh[wave][lane] = 0.0625f * s;
  }
  __syncthreads();
  bool on = (lane == sel[0]) | (lane == sel[1]) | (lane == sel[2]) | (lane == sel[3]);
  us8 lo, hi;
  #pragma unroll
  for (int r = 0; r < 8; ++r) lo[r] = on ? f2bf(vsh[wave][r])     : (unsigned short)0;
  #pragma unroll
  for (int r = 0; r < 8; ++r) hi[r] = on ? f2bf(vsh[wave][r + 8]) : (unsigned short)0;
  us8* d = (us8*)(XG + (size_t)t * KTOT + H + lane * RANK);
  d[0] = lo; d[1] = hi;
}

__device__ __forceinline__ void gload_lds16(const void* gsrc, void* ldst) {
  __builtin_amdgcn_global_load_lds(
      (const __attribute__((address_space(1))) unsigned int*)gsrc,
      (__attribute__((address_space(3))) unsigned int*)ldst, 16, 0, 0);
}

// ------------------------------------------------------------------
// GEMM1 (pre-split): vecs[8192,1024] = Xhi@Ahi^T + Xhi@Alo^T + Xlo@Ahi^T, all bf16.
// 128x128 tile, 4 waves (2x2), BK=32, global_load_lds staging, 48 MFMA / K-step.
// LDS swizzle: 16B slot ^= (row>>1)&3 (pre-swizzled global src + swizzled read).
// ------------------------------------------------------------------
__global__ __launch_bounds__(256, 2) void gemm1_kernel(
    const unsigned short* __restrict__ Xhi,   // lda KTOT
    const unsigned short* __restrict__ Xlo,   // lda H
    const unsigned short* __restrict__ Ahi,   // ldb H
    const unsigned short* __restrict__ Alo,   // ldb H
    float* __restrict__ C) {                  // ldc KG
  __shared__ unsigned short AsH[128 * 32];
  __shared__ unsigned short AsL[128 * 32];
  __shared__ unsigned short BsH[128 * 32];
  __shared__ unsigned short BsL[128 * 32];
  const int tid = threadIdx.x;
  const int lane = tid & 63, wave = tid >> 6;
  const int wr = wave >> 1, wc = wave & 1;
  const int bm = blockIdx.x, bn = blockIdx.y;

  v4f acc[4][4];
  #pragma unroll
  for (int i = 0; i < 4; ++i)
    #pragma unroll
    for (int j = 0; j < 4; ++j)
      acc[i][j] = (v4f){0.f, 0.f, 0.f, 0.f};

  const unsigned short* XhiB = Xhi + (size_t)(bm * 128) * KTOT;
  const unsigned short* XloB = Xlo + (size_t)(bm * 128) * H;
  const unsigned short* AhiB = Ahi + (size_t)(bn * 128) * H;
  const unsigned short* AloB = Alo + (size_t)(bn * 128) * H;

  const int rA = lane & 15;
  // swizzled read slot: logical slot = lane>>4, physical ^= (row>>1)&3 (row ≡ rA mod 16)
  const int kkx = (((lane >> 4) ^ ((rA >> 1) & 3)) << 3);

  for (int k0 = 0; k0 < H; k0 += 32) {
    #pragma unroll
    for (int rnd = 0; rnd < 2; ++rnd) {
      int e = rnd * 256 + tid;           // 16B unit within a 128x32 bf16 tile
      int r = e >> 2;
      int c8 = (((e & 3) ^ ((e >> 3) & 3)) << 3);   // pre-swizzled source slot
      gload_lds16(XhiB + (size_t)r * KTOT + k0 + c8, (char*)AsH + (size_t)e * 16);
      gload_lds16(XloB + (size_t)r * H    + k0 + c8, (char*)AsL + (size_t)e * 16);
      gload_lds16(AhiB + (size_t)r * H    + k0 + c8, (char*)BsH + (size_t)e * 16);
      gload_lds16(AloB + (size_t)r * H    + k0 + c8, (char*)BsL + (size_t)e * 16);
    }
    __syncthreads();
    v8bf ah[4], al[4], bh[4], bl[4];
    #pragma unroll
    for (int i = 0; i < 4; ++i) {
      ah[i] = *(const v8bf*)&AsH[(wr * 64 + i * 16 + rA) * 32 + kkx];
      al[i] = *(const v8bf*)&AsL[(wr * 64 + i * 16 + rA) * 32 + kkx];
    }
    #pragma unroll
    for (int j = 0; j < 4; ++j) {
      bh[j] = *(const v8bf*)&BsH[(wc * 64 + j * 16 + rA) * 32 + kkx];
      bl[j] = *(const v8bf*)&BsL[(wc * 64 + j * 16 + rA) * 32 + kkx];
    }
    #pragma unroll
    for (int i = 0; i < 4; ++i)
      #pragma unroll
      for (int j = 0; j < 4; ++j) {
        acc[i][j] = __builtin_amdgcn_mfma_f32_16x16x32_bf16(ah[i], bh[j], acc[i][j], 0, 0, 0);
        acc[i][j] = __builtin_amdgcn_mfma_f32_16x16x32_bf16(ah[i], bl[j], acc[i][j], 0, 0, 0);
        acc[i][j] = __builtin_amdgcn_mfma_f32_16x16x32_bf16(al[i], bh[j], acc[i][j], 0, 0, 0);
      }
    __syncthreads();
  }

  const int rowbase = bm * 128 + wr * 64;
  const int colbase = bn * 128 + wc * 64;
  #pragma unroll
  for (int i = 0; i < 4; ++i) {
    int r0 = rowbase + i * 16 + ((lane >> 4) << 2);
    #pragma unroll
    for (int j = 0; j < 4; ++j) {
      int col = colbase + j * 16 + (lane & 15);
      #pragma unroll
      for (int q = 0; q < 4; ++q)
        C[(size_t)(r0 + q) * KG + col] = acc[i][j][q];
    }
  }
}

// ------------------------------------------------------------------
// GEMM2: out[8192,2048] = XG[8192,3072]@WB[2048,3072]^T + bias.
// 256x256 tile, BK=64, 8 waves (2Mx4N, per-wave 128x64), 8-phase schedule:
// K-half LDS regions (16KB each, x2 dbuf = 128KB), counted vmcnt(8), setprio,
// bank swizzle: 16B slot ^= (row>>1)&3 on both stage-src and ds_read.
// ------------------------------------------------------------------
#define BAR() asm volatile("s_waitcnt lgkmcnt(0)\n\ts_barrier" ::: "memory")
#define VM8() asm volatile("s_waitcnt vmcnt(8)" ::: "memory")

#define STAGE(regionUS, panel, kelem) do {                                        \
  gload_lds16((panel) + aoff0 + (kelem), (char*)(regionUS) + tid * 16);           \
  gload_lds16((panel) + aoff1 + (kelem), (char*)(regionUS) + 8192 + tid * 16);    \
} while (0)

#define PHASE(mh, RAr, RBr, ISSUE, DOVM) do {                                     \
  if ((mh) == 0) {                                                                \
    _Pragma("unroll")                                                             \
    for (int j = 0; j < 4; ++j)                                                   \
      bfr[j] = *(const v8bf*)((const char*)(RBr) + bbyte + j * 1024);             \
  }                                                                               \
  _Pragma("unroll")                                                               \
  for (int i = 0; i < 4; ++i)                                                     \
    af[i] = *(const v8bf*)((const char*)(RAr) + abyte + ((mh)*4 + i) * 1024);     \
  ISSUE;                                                                          \
  BAR();                                                                          \
  __builtin_amdgcn_s_setprio(1);                                                  \
  _Pragma("unroll")                                                               \
  for (int i = 0; i < 4; ++i)                                                     \
    _Pragma("unroll")                                                             \
    for (int j = 0; j < 4; ++j)                                                   \
      acc[(mh)*4 + i][j] = __builtin_amdgcn_mfma_f32_16x16x32_bf16(               \
          af[i], bfr[j], acc[(mh)*4 + i][j], 0, 0, 0);                            \
  __builtin_amdgcn_s_setprio(0);                                                  \
  DOVM;                                                                           \
  BAR();                                                                          \
} while (0)

__global__ __launch_bounds__(512, 1) void gemm2_8ph_kernel(
    const unsigned short* __restrict__ Xg, const unsigned short* __restrict__ Wb,
    float* __restrict__ C, const float* __restrict__ bias) {
  __shared__ unsigned short lds[65536];   // 128 KB
  const int tid = threadIdx.x;
  const int lane = tid & 63, wid = tid >> 6;
  const int wr = wid >> 2, wc = wid & 3;
  const int rA = lane & 15, grp = lane >> 4;
  const int grpx = (grp ^ ((rA >> 1) & 3)) << 4;   // swizzled 16B slot (byte)

  const int bid = blockIdx.x;
  const int bn = bid & 7, bm = bid >> 3;           // each XCD owns one bn column

  const unsigned short* Ap = Xg + (size_t)(bm * 256) * KTOT;
  const unsigned short* Bp = Wb + (size_t)(bn * 256) * KTOT;

  // staging: LDS chunk u = l*512+tid at byte u*16 (linear dest); source row u>>2,
  // pre-swizzled 8-elem slot (u&3)^((u>>3)&3)
  const int srow = tid >> 2;
  const int scol = ((tid & 3) ^ ((tid >> 3) & 3)) << 3;
  const size_t aoff0 = (size_t)srow * KTOT + scol;
  const size_t aoff1 = (size_t)(srow + 128) * KTOT + scol;

  // LDS regions (ushort offsets): buf b at b*32768; A-k0 +0, A-k1 +8192,
  // B-k0 +16384, B-k1 +24576
  unsigned short* A0k0 = lds;
  unsigned short* A0k1 = lds + 8192;
  unsigned short* B0k0 = lds + 16384;
  unsigned short* B0k1 = lds + 24576;
  unsigned short* A1k0 = lds + 32768;
  unsigned short* A1k1 = lds + 40960;
  unsigned short* B1k0 = lds + 49152;
  unsigned short* B1k1 = lds + 57344;

  const int abyte = (wr * 128 + rA) * 64 + grpx;   // + (mi*16)*64 per fragment
  const int bbyte = (wc * 64 + rA) * 64 + grpx;    // + (nj*16)*64

  v4f acc[8][4];
  #pragma unroll
  for (int i = 0; i < 8; ++i)
    #pragma unroll
    for (int j = 0; j < 4; ++j)
      acc[i][j] = (v4f){0.f, 0.f, 0.f, 0.f};
  v8bf af[4], bfr[4];

  // prologue: tile0 (4 halves) + tile1 k0 halves; wait for tile0-k0.
  STAGE(A0k0, Ap, 0);
  STAGE(B0k0, Bp, 0);
  STAGE(A0k1, Ap, 32);
  STAGE(B0k1, Bp, 32);
  STAGE(A1k0, Ap, 64);
  STAGE(B1k0, Bp, 64);
  VM8();
  BAR();

  #pragma unroll 1
  for (int t = 0; t < NT2; t += 2) {
    const int k1a = (t + 1) * 64 + 32;                          // k1(t+1)
    const int k0a = (t + 2 < NT2 ? t + 2 : NT2 - 1) * 64;       // k0(t+2)
    const int k1b = (t + 2 < NT2 ? t + 2 : NT2 - 1) * 64 + 32;  // k1(t+2)
    const int k0b = (t + 3 < NT2 ? t + 3 : NT2 - 1) * 64;       // k0(t+3)
    // tile t (buf0)
    PHASE(0, A0k0, B0k0, STAGE(A1k1, Ap, k1a), ((void)0));
    PHASE(1, A0k0, B0k0, STAGE(B1k1, Bp, k1a), VM8());
    PHASE(0, A0k1, B0k1, STAGE(A0k0, Ap, k0a), ((void)0));
    PHASE(1, A0k1, B0k1, STAGE(B0k0, Bp, k0a), VM8());
    // tile t+1 (buf1)
    PHASE(0, A1k0, B1k0, STAGE(A0k1, Ap, k1b), ((void)0));
    PHASE(1, A1k0, B1k0, STAGE(B0k1, Bp, k1b), VM8());
    PHASE(0, A1k1, B1k1, STAGE(A1k0, Ap, k0b), ((void)0));
    PHASE(1, A1k1, B1k1, STAGE(B1k0, Bp, k0b), VM8());
  }

  // epilogue
  const int row0 = bm * 256 + wr * 128 + (grp << 2);
  const int col0 = bn * 256 + wc * 64 + rA;
  float bv[4];
  #pragma unroll
  for (int j = 0; j < 4; ++j) bv[j] = bias[col0 + j * 16];
  #pragma unroll
  for (int mi = 0; mi < 8; ++mi)
    #pragma unroll
    for (int j = 0; j < 4; ++j)
      #pragma unroll
      for (int q = 0; q < 4; ++q)
        C[(size_t)(row0 + mi * 16 + q) * JDIM + col0 + j * 16] = acc[mi][j][q] + bv[j];
}

extern "C" void kernel_launch(void* const* d_in, const int* in_sizes, int n_in,
                              void* d_out, int out_size, void* d_ws, size_t ws_size,
                              hipStream_t stream) {
  const float* x    = (const float*)d_in[0];
  const float* A    = (const float*)d_in[1];
  const float* Bb   = (const float*)d_in[2];
  const float* W    = (const float*)d_in[3];
  const float* bias = (const float*)d_in[4];
  float* out = (float*)d_out;

  char* ws = (char*)d_ws;
  // ws layout: XG bf16 [8192][3072] (48M) | WB bf16 [2048][3072] (12M) |
  //            Ahi bf16 [1024][2048] (4M) | Alo bf16 [1024][2048] (4M)   = 68M
  unsigned short* XG  = (unsigned short*)ws;
  unsigned short* WB  = (unsigned short*)(ws + (size_t)48 * 1024 * 1024);
  unsigned short* Ahi = (unsigned short*)(ws + (size_t)60 * 1024 * 1024);
  unsigned short* Alo = (unsigned short*)(ws + (size_t)64 * 1024 * 1024);
  // d_out doubles as pre-gemm2 scratch: lower 32MB vecs f32, upper 32MB x_lo bf16.
  float* vecs         = (float*)d_out;
  unsigned short* XLO = (unsigned short*)((char*)d_out + (size_t)32 * 1024 * 1024);

  cast_x_split_kernel<<<TOKENS, 256, 0, stream>>>(x, XG, XLO);
  cast_a_split_kernel<<<KG / 1, 256, 0, stream>>>(A, Ahi, Alo);
  cast2048_kernel<<<JDIM, 256, 0, stream>>>(W, WB, KTOT);
  cast_b_kernel<<<512, 256, 0, stream>>>(Bb, WB);

  // vecs = x @ A^T in near-fp32 (3-term bf16 split), M=8192 N=1024 K=2048
  gemm1_kernel<<<dim3(TOKENS / 128, KG / 128), 256, 0, stream>>>(
      XG, XLO, Ahi, Alo, vecs);

  // routing -> G block of XG
  route_kernel<<<TOKENS / 4, 256, 0, stream>>>(vecs, XG);

  // out = [Xb|G] @ [Wb|Bt]^T + bias   (M=8192, N=2048, K=3072), 8-phase 256² tile
  gemm2_8ph_kernel<<<256, 512, 0, stream>>>(XG, WB, out, bias);
}